// Round 13
// baseline (106.815 us; speedup 1.0000x reference)
//
#include <hip/hip_runtime.h>
#include <hip/hip_fp16.h>

#define NN 50000
#define NE 800000
#define FIN 128
#define NH 4
#define HD 32
#define FOUT 128   // NH*HD
#define NEG 0.2f
#define NB_W    ((256 * FIN + 255) / 256) // 128
#define N_GEMM  391                  // 128-row stripes, BN=256 (full width)
#define NBKT    98                   // dst>>9 buckets (512 nodes each)
#define CHUNK   4096                 // edges per hist/scatter chunk
#define NCHUNK  ((NE + CHUNK - 1) / CHUNK)  // 196
#define GB_GRID (NCHUNK * 3)         // 588: b%3==0 -> scatter, else gemm (391 used)
#define BCAP    12288                // binB LDS segment capacity (mean 8163, max ~8600)

typedef __attribute__((ext_vector_type(8))) short bf16x8;
typedef __attribute__((ext_vector_type(4))) float f32x4;

__device__ __forceinline__ uint f2bf_u(float f) {
    uint u = __float_as_uint(f);
    u += 0x7FFF + ((u >> 16) & 1);   // round-to-nearest-even
    return u >> 16;
}
__device__ __forceinline__ ushort f2bf(float f) { return (ushort)f2bf_u(f); }

template<int CTRL>
__device__ __forceinline__ float dpp_add(float x) {
    int y = __builtin_amdgcn_update_dpp(0, __float_as_int(x), CTRL, 0xF, 0xF, false);
    return x + __int_as_float(y);
}
#define DPP_QUAD_XOR1 0xB1   // quad_perm [1,0,3,2]
#define DPP_QUAD_XOR2 0x4E   // quad_perm [2,3,0,1]

__device__ __forceinline__ __half2 u2h(uint u) { return __builtin_bit_cast(__half2, u); }
__device__ __forceinline__ uint h2u(__half2 h) { return __builtin_bit_cast(uint, h); }

// ROCm 7.2 hip_fp16.h lacks __hmax2 — emit v_pk_max_f16 directly
__device__ __forceinline__ __half2 hmax2(__half2 a, __half2 b) {
    uint r, ua = h2u(a), ub = h2u(b);
    asm("v_pk_max_f16 %0, %1, %2" : "=v"(r) : "v"(ua), "v"(ub));
    return u2h(r);
}

// ---------------- hist chunks + Wt conversion (one launch, independent roles) ----------------
__global__ __launch_bounds__(256) void hist_wt_k(
    const int* __restrict__ dst, int* __restrict__ chunk_hist,
    const float* __restrict__ Wsrc, const float* __restrict__ Wdst,
    ushort* __restrict__ Wt)
{
    __shared__ int hist[NBKT];
    const int b = blockIdx.x;
    const int tid = threadIdx.x;
    if (b < NCHUNK) {
        const int e0 = b * CHUNK;
        for (int t = tid; t < NBKT; t += 256) hist[t] = 0;
        __syncthreads();
        #pragma unroll
        for (int k = 0; k < 16; ++k) {
            const int e = e0 + k * 256 + tid;
            if (e < NE) atomicAdd(&hist[dst[e] >> 9], 1);
        }
        __syncthreads();
        for (int t = tid; t < NBKT; t += 256)
            chunk_hist[b * NBKT + t] = hist[t];
    } else {
        int t = (b - NCHUNK) * 256 + tid;
        if (t >= 256 * FIN) return;
        int n = t >> 7, k = t & 127;
        float v = (n < 128) ? Wsrc[k * 128 + n] : Wdst[k * 128 + (n - 128)];
        Wt[t] = f2bf(v);
    }
}

// ---------------- per-bucket scan over chunks ----------------
__global__ __launch_bounds__(256) void scan_chunks_k(
    const int* __restrict__ chunk_hist, int* __restrict__ chunk_base, int* __restrict__ btotal)
{
    __shared__ int sh[256];
    const int b = blockIdx.x, t = threadIdx.x;
    const int v = (t < NCHUNK) ? chunk_hist[t * NBKT + b] : 0;
    sh[t] = v;
    __syncthreads();
    for (int off = 1; off < 256; off <<= 1) {
        int add = (t >= off) ? sh[t - off] : 0;
        __syncthreads();
        sh[t] += add;
        __syncthreads();
    }
    if (t < NCHUNK) chunk_base[t * NBKT + b] = sh[t] - v;   // exclusive
    if (t == 255) btotal[b] = sh[255];
}

// ---------------- cross-bucket exclusive scan + attn->f16 ----------------
__global__ __launch_bounds__(256) void scan_buckets_k(
    const int* __restrict__ btotal, int* __restrict__ bkbase,
    const float* __restrict__ attn, __half* __restrict__ attn_h)
{
    __shared__ int sh[256];
    const int t = threadIdx.x;
    const int v = (t < NBKT) ? btotal[t] : 0;
    sh[t] = v;
    __syncthreads();
    for (int off = 1; off < 256; off <<= 1) {
        int add = (t >= off) ? sh[t - off] : 0;
        __syncthreads();
        sh[t] += add;
        __syncthreads();
    }
    if (t < NBKT) bkbase[t] = sh[t] - v;     // exclusive
    if (t == 0) bkbase[NBKT] = NE;
    if (t < FOUT) attn_h[t] = __float2half(attn[t]);
}

// ---------------- FUSED: MFMA GEMM (BM=128, BN=256 full-width: x read ONCE) + scatter ----------------
// b % 3 == 0 -> scatter chunk b/3 (196); else gemm stripe g = b - b/3 - 1 (391 used)
__global__ __launch_bounds__(256) void gemm_scatter_k(
    const float* __restrict__ x, const ushort* __restrict__ Wt,
    const float* __restrict__ bsrc, const float* __restrict__ bdst,
    __half* __restrict__ fsfd,
    const int* __restrict__ dst, const int* __restrict__ src,
    const int* __restrict__ bkbase, const int* __restrict__ chunk_base,
    uint* __restrict__ ebuf)
{
    __shared__ ushort As[128 * 128];   // 32 KB
    __shared__ ushort Bs[256 * 128];   // 64 KB (all of Wt)
    __shared__ int cur[NBKT];
    const int b = blockIdx.x;
    const int tid = threadIdx.x;

    if (b % 3 == 0) {
        // ---- scatter role: positions precomputed, LDS cursors only ----
        const int chunk = b / 3;
        for (int t = tid; t < NBKT; t += 256)
            cur[t] = bkbase[t] + chunk_base[chunk * NBKT + t];
        __syncthreads();
        const int e0 = chunk * CHUNK;
        #pragma unroll
        for (int k = 0; k < 16; ++k) {
            const int e = e0 + k * 256 + tid;
            if (e < NE) {
                const int d = dst[e];
                const int p = atomicAdd(&cur[d >> 9], 1);   // LDS atomic
                ebuf[p] = ((uint)d << 16) | (uint)src[e];
            }
        }
        return;
    }

    // ---- gemm role: one 128-row stripe, ALL 256 output cols ----
    const int g = b - b / 3 - 1;
    if (g >= N_GEMM) return;
    const int bm = g * 128;

    // A tile: read f32 x ONCE, convert to bf16 in-register, swizzled LDS write
    for (int q = tid; q < 128 * 16; q += 256) {
        int r = q >> 4, c16 = q & 15;
        int row = bm + r;
        uint4 o = make_uint4(0u, 0u, 0u, 0u);
        if (row < NN) {
            const float4 a = *(const float4*)&x[(size_t)row * FIN + c16 * 8];
            const float4 c = *(const float4*)&x[(size_t)row * FIN + c16 * 8 + 4];
            o.x = f2bf_u(a.x) | (f2bf_u(a.y) << 16);
            o.y = f2bf_u(a.z) | (f2bf_u(a.w) << 16);
            o.z = f2bf_u(c.x) | (f2bf_u(c.y) << 16);
            o.w = f2bf_u(c.z) | (f2bf_u(c.w) << 16);
        }
        int off = r * 256 + ((c16 * 16) ^ ((r & 7) << 4));
        *(uint4*)((char*)As + off) = o;
    }
    // B tile: entire Wt (256 rows)
    for (int q = tid; q < 256 * 16; q += 256) {
        int r = q >> 4, c16 = q & 15;
        uint4 v = *(const uint4*)&Wt[r * FIN + c16 * 8];
        int off = r * 256 + ((c16 * 16) ^ ((r & 7) << 4));
        *(uint4*)((char*)Bs + off) = v;
    }
    __syncthreads();

    const int wid = tid >> 6, lane = tid & 63;
    const int wr = (wid >> 1) * 64;        // 2 wave-rows
    const int wc = (wid & 1) * 128;        // 2 wave-cols
    const int lrow = lane & 15;
    const int lk = (lane >> 4) * 16;

    f32x4 acc[4][8] = {};
    #pragma unroll
    for (int kk = 0; kk < 4; ++kk) {
        bf16x8 a[4], bb[8];
        #pragma unroll
        for (int m = 0; m < 4; ++m) {
            int r = wr + m * 16 + lrow;
            int off = r * 256 + ((kk * 64 + lk) ^ ((r & 7) << 4));
            a[m] = *(bf16x8*)((char*)As + off);
        }
        #pragma unroll
        for (int n = 0; n < 8; ++n) {
            int r = wc + n * 16 + lrow;
            int off = r * 256 + ((kk * 64 + lk) ^ ((r & 7) << 4));
            bb[n] = *(bf16x8*)((char*)Bs + off);
        }
        #pragma unroll
        for (int m = 0; m < 4; ++m)
            #pragma unroll
            for (int n = 0; n < 8; ++n)
                acc[m][n] = __builtin_amdgcn_mfma_f32_16x16x32_bf16(a[m], bb[n], acc[m][n], 0, 0, 0);
    }

    #pragma unroll
    for (int m = 0; m < 4; ++m) {
        #pragma unroll
        for (int n = 0; n < 8; ++n) {
            int gcol = wc + n * 16 + (lane & 15);
            float bias = (gcol < 128) ? bsrc[gcol] : bdst[gcol - 128];
            #pragma unroll
            for (int r = 0; r < 4; ++r) {
                int grow = bm + wr + m * 16 + (lane >> 4) * 4 + r;
                if (grow < NN)
                    fsfd[(size_t)grow * 256 + gcol] = __float2half(acc[m][n][r] + bias);
            }
        }
    }
}

// ---------------- binB: per-bucket rowptr build (LDS) + coalesced nbr ----------------
__global__ __launch_bounds__(256) void binB_k(
    const uint* __restrict__ ebuf, const int* __restrict__ bkbase,
    int* __restrict__ rowptr, ushort* __restrict__ nbr)
{
    __shared__ int cnt_s[512];
    __shared__ int ps[256];
    __shared__ ushort buf[BCAP];
    const int b = blockIdx.x;
    const int tid = threadIdx.x;
    const int node0 = b << 9;
    const int nodes = (node0 + 512 < NN) ? 512 : (NN - node0);
    const int segbase = bkbase[b];
    const int segend  = bkbase[b + 1];
    const int seglen  = segend - segbase;

    cnt_s[tid] = 0;
    cnt_s[tid + 256] = 0;
    __syncthreads();
    for (int i = segbase + tid; i < segend; i += 256)
        atomicAdd(&cnt_s[(int)(ebuf[i] >> 16) - node0], 1);   // LDS atomic
    __syncthreads();

    // 512-wide exclusive prefix scan (2 elems/thread)
    const int c0 = cnt_s[2 * tid], c1 = cnt_s[2 * tid + 1];
    const int pair = c0 + c1;
    ps[tid] = pair;
    __syncthreads();
    for (int off = 1; off < 256; off <<= 1) {
        int add = (tid >= off) ? ps[tid - off] : 0;
        __syncthreads();
        ps[tid] += add;
        __syncthreads();
    }
    const int ex = ps[tid] - pair;
    __syncthreads();
    cnt_s[2 * tid] = ex;
    cnt_s[2 * tid + 1] = ex + c0;
    if (2 * tid < nodes)     rowptr[node0 + 2 * tid]     = segbase + ex;
    if (2 * tid + 1 < nodes) rowptr[node0 + 2 * tid + 1] = segbase + ex + c0;
    if (b == NBKT - 1 && tid == 0) rowptr[NN] = segend;
    __syncthreads();

    if (seglen <= BCAP) {
        for (int i = segbase + tid; i < segend; i += 256) {
            const uint e = ebuf[i];
            const int d = (int)(e >> 16) - node0;
            const int p = atomicAdd(&cnt_s[d], 1);
            buf[p] = (ushort)(e & 0xffffu);
        }
        __syncthreads();
        for (int i = tid; i < seglen; i += 256)
            nbr[segbase + i] = buf[i];
    } else {
        // correctness fallback: direct (uncoalesced) global writes
        for (int i = segbase + tid; i < segend; i += 256) {
            const uint e = ebuf[i];
            const int d = (int)(e >> 16) - node0;
            const int p = atomicAdd(&cnt_s[d], 1);
            nbr[segbase + p] = (ushort)(e & 0xffffu);
        }
    }
}

// ---------------- Fused per-node GAT kernel (packed f16, 4 gathers in flight) ----------------
// One wave per node. ql = lane&15 owns elems {8ql..8ql+7} (4 half2); quarter-waves
// process 4 edges concurrently; i-step 16 keeps 4 row-gathers in flight per quarter.
__global__ __launch_bounds__(256) void gat_node_k(
    const __half* __restrict__ fsfd, const __half* __restrict__ attn_h,
    const int* __restrict__ rowptr, const ushort* __restrict__ nbr,
    float* __restrict__ out)
{
    const int node = blockIdx.x * 4 + (threadIdx.x >> 6);
    const int lane = threadIdx.x & 63;
    const int ql = lane & 15;
    const int q  = lane >> 4;

    const uint4 ufd = *(const uint4*)&fsfd[(size_t)node * 256 + 128 + 8 * ql];
    const __half2 fd0 = u2h(ufd.x), fd1 = u2h(ufd.y), fd2 = u2h(ufd.z), fd3 = u2h(ufd.w);
    const uint4 uav = *(const uint4*)&attn_h[8 * ql];
    const __half2 av0 = u2h(uav.x), av1 = u2h(uav.y), av2 = u2h(uav.z), av3 = u2h(uav.w);
    const __half2 k02 = __float2half2_rn(NEG);

    const int beg = rowptr[node];
    const int end = rowptr[node + 1];

    float den = 0.f;
    __half2 acc0 = u2h(0), acc1 = u2h(0), acc2 = u2h(0), acc3 = u2h(0);

    for (int i = beg; i < end; i += 16) {
        #pragma unroll
        for (int j = 0; j < 4; ++j) {
            const int idx = i + 4 * j + q;
            const bool valid = idx < end;
            const int s = nbr[valid ? idx : end - 1];
            const uint4 u = *(const uint4*)&fsfd[(size_t)s * 256 + 8 * ql];
            const __half2 f0 = u2h(u.x), f1 = u2h(u.y), f2 = u2h(u.z), f3 = u2h(u.w);
            __half2 v0 = __hadd2(f0, fd0), v1 = __hadd2(f1, fd1);
            __half2 v2 = __hadd2(f2, fd2), v3 = __hadd2(f3, fd3);
            v0 = hmax2(v0, __hmul2(v0, k02));
            v1 = hmax2(v1, __hmul2(v1, k02));
            v2 = hmax2(v2, __hmul2(v2, k02));
            v3 = hmax2(v3, __hmul2(v3, k02));
            __half2 sch = __hmul2(v0, av0);
            sch = __hfma2(v1, av1, sch);
            sch = __hfma2(v2, av2, sch);
            sch = __hfma2(v3, av3, sch);
            float sc = __low2float(sch) + __high2float(sch);
            sc = dpp_add<DPP_QUAD_XOR1>(sc);
            sc = dpp_add<DPP_QUAD_XOR2>(sc);
            float ex = __expf(sc);
            ex = valid ? ex : 0.f;
            den += ex;
            const __half2 exh = __float2half2_rn(ex);
            acc0 = __hfma2(exh, f0, acc0);
            acc1 = __hfma2(exh, f1, acc1);
            acc2 = __hfma2(exh, f2, acc2);
            acc3 = __hfma2(exh, f3, acc3);
        }
    }

    den += __shfl_xor(den, 16, 64);
    den += __shfl_xor(den, 32, 64);
    uint ua0 = h2u(acc0), ua1 = h2u(acc1), ua2 = h2u(acc2), ua3 = h2u(acc3);
    ua0 = h2u(__hadd2(u2h(ua0), u2h((uint)__shfl_xor((int)ua0, 16, 64))));
    ua1 = h2u(__hadd2(u2h(ua1), u2h((uint)__shfl_xor((int)ua1, 16, 64))));
    ua2 = h2u(__hadd2(u2h(ua2), u2h((uint)__shfl_xor((int)ua2, 16, 64))));
    ua3 = h2u(__hadd2(u2h(ua3), u2h((uint)__shfl_xor((int)ua3, 16, 64))));
    ua0 = h2u(__hadd2(u2h(ua0), u2h((uint)__shfl_xor((int)ua0, 32, 64))));
    ua1 = h2u(__hadd2(u2h(ua1), u2h((uint)__shfl_xor((int)ua1, 32, 64))));
    ua2 = h2u(__hadd2(u2h(ua2), u2h((uint)__shfl_xor((int)ua2, 32, 64))));
    ua3 = h2u(__hadd2(u2h(ua3), u2h((uint)__shfl_xor((int)ua3, 32, 64))));

    if (q == 0) {
        const float inv = (den > 0.f) ? 1.f / den : 0.f;
        float4 o0, o1;
        o0.x = fmaxf(__low2float(u2h(ua0))  * inv, 0.f);
        o0.y = fmaxf(__high2float(u2h(ua0)) * inv, 0.f);
        o0.z = fmaxf(__low2float(u2h(ua1))  * inv, 0.f);
        o0.w = fmaxf(__high2float(u2h(ua1)) * inv, 0.f);
        o1.x = fmaxf(__low2float(u2h(ua2))  * inv, 0.f);
        o1.y = fmaxf(__high2float(u2h(ua2)) * inv, 0.f);
        o1.z = fmaxf(__low2float(u2h(ua3))  * inv, 0.f);
        o1.w = fmaxf(__high2float(u2h(ua3)) * inv, 0.f);
        *(float4*)&out[(size_t)node * FOUT + 8 * ql] = o0;
        *(float4*)&out[(size_t)node * FOUT + 8 * ql + 4] = o1;
    }
}

extern "C" void kernel_launch(void* const* d_in, const int* in_sizes, int n_in,
                              void* d_out, int out_size, void* d_ws, size_t ws_size,
                              hipStream_t stream)
{
    const float* x    = (const float*)d_in[0];
    const int*   src  = (const int*)d_in[1];
    const int*   dst  = (const int*)d_in[2];
    const float* Wsrc = (const float*)d_in[3];
    const float* bsrc = (const float*)d_in[4];
    const float* Wdst = (const float*)d_in[5];
    const float* bdst = (const float*)d_in[6];
    const float* attn = (const float*)d_in[7];
    float* out = (float*)d_out;

    ushort* Wt      = (ushort*)d_ws;                      // 256*128 bf16
    __half* fsfd    = (__half*)(Wt + 256 * FIN);          // NN*256 f16
    int* chunk_hist = (int*)(fsfd + (size_t)NN * 256);    // NCHUNK*NBKT
    int* chunk_base = chunk_hist + NCHUNK * NBKT;         // NCHUNK*NBKT
    int* btotal     = chunk_base + NCHUNK * NBKT;         // NBKT
    int* bkbase     = btotal + NBKT;                      // NBKT+1
    int* rowptr     = bkbase + NBKT + 1;                  // NN+1
    uint* ebuf      = (uint*)(rowptr + NN + 1);           // NE packed (d<<16)|s
    ushort* nbr     = (ushort*)(ebuf + NE);               // NE u16
    __half* attn_h  = (__half*)(nbr + NE);                // 128 f16

    hist_wt_k<<<NCHUNK + NB_W, 256, 0, stream>>>(dst, chunk_hist, Wsrc, Wdst, Wt);
    scan_chunks_k<<<NBKT, 256, 0, stream>>>(chunk_hist, chunk_base, btotal);
    scan_buckets_k<<<1, 256, 0, stream>>>(btotal, bkbase, attn, attn_h);
    gemm_scatter_k<<<GB_GRID, 256, 0, stream>>>(x, Wt, bsrc, bdst, fsfd,
                                                dst, src, bkbase, chunk_base, ebuf);
    binB_k<<<NBKT, 256, 0, stream>>>(ebuf, bkbase, rowptr, nbr);
    gat_node_k<<<(NN + 3) / 4, 256, 0, stream>>>(fsfd, attn_h, rowptr, nbr, out);
}

// Round 14
// 91.387 us; speedup vs baseline: 1.1688x; 1.1688x over previous
//
#include <hip/hip_runtime.h>
#include <hip/hip_fp16.h>

#define NN 50000
#define NE 800000
#define FIN 128
#define NH 4
#define HD 32
#define FOUT 128   // NH*HD
#define NEG 0.2f
#define NB_W    ((256 * FIN + 255) / 256) // 128
#define N_GEMM  391                  // 128-row stripes; each block does all 4 col-tiles
#define NBKT    98                   // dst>>9 buckets (512 nodes each)
#define CHUNK   4096                 // edges per hist/scatter chunk
#define NCHUNK  ((NE + CHUNK - 1) / CHUNK)  // 196
#define GB_GRID (NCHUNK * 3)         // 588: b%3==0 -> scatter (196), else gemm (391 used)
#define BCAP    12288                // binB LDS segment capacity (mean 8163, max ~8600)

typedef __attribute__((ext_vector_type(8))) short bf16x8;
typedef __attribute__((ext_vector_type(4))) float f32x4;

__device__ __forceinline__ uint f2bf_u(float f) {
    uint u = __float_as_uint(f);
    u += 0x7FFF + ((u >> 16) & 1);   // round-to-nearest-even
    return u >> 16;
}
__device__ __forceinline__ ushort f2bf(float f) { return (ushort)f2bf_u(f); }

template<int CTRL>
__device__ __forceinline__ float dpp_add(float x) {
    int y = __builtin_amdgcn_update_dpp(0, __float_as_int(x), CTRL, 0xF, 0xF, false);
    return x + __int_as_float(y);
}
#define DPP_QUAD_XOR1 0xB1   // quad_perm [1,0,3,2]
#define DPP_QUAD_XOR2 0x4E   // quad_perm [2,3,0,1]

__device__ __forceinline__ __half2 u2h(uint u) { return __builtin_bit_cast(__half2, u); }
__device__ __forceinline__ uint h2u(__half2 h) { return __builtin_bit_cast(uint, h); }

// ROCm 7.2 hip_fp16.h lacks __hmax2 — emit v_pk_max_f16 directly
__device__ __forceinline__ __half2 hmax2(__half2 a, __half2 b) {
    uint r, ua = h2u(a), ub = h2u(b);
    asm("v_pk_max_f16 %0, %1, %2" : "=v"(r) : "v"(ua), "v"(ub));
    return u2h(r);
}

// ---------------- hist chunks + Wt conversion (one launch, independent roles) ----------------
__global__ __launch_bounds__(256) void hist_wt_k(
    const int* __restrict__ dst, int* __restrict__ chunk_hist,
    const float* __restrict__ Wsrc, const float* __restrict__ Wdst,
    ushort* __restrict__ Wt)
{
    __shared__ int hist[NBKT];
    const int b = blockIdx.x;
    const int tid = threadIdx.x;
    if (b < NCHUNK) {
        const int e0 = b * CHUNK;
        for (int t = tid; t < NBKT; t += 256) hist[t] = 0;
        __syncthreads();
        #pragma unroll
        for (int k = 0; k < 16; ++k) {
            const int e = e0 + k * 256 + tid;
            if (e < NE) atomicAdd(&hist[dst[e] >> 9], 1);
        }
        __syncthreads();
        for (int t = tid; t < NBKT; t += 256)
            chunk_hist[b * NBKT + t] = hist[t];
    } else {
        int t = (b - NCHUNK) * 256 + tid;
        if (t >= 256 * FIN) return;
        int n = t >> 7, k = t & 127;
        float v = (n < 128) ? Wsrc[k * 128 + n] : Wdst[k * 128 + (n - 128)];
        Wt[t] = f2bf(v);
    }
}

// ---------------- per-bucket scan over chunks ----------------
__global__ __launch_bounds__(256) void scan_chunks_k(
    const int* __restrict__ chunk_hist, int* __restrict__ chunk_base, int* __restrict__ btotal)
{
    __shared__ int sh[256];
    const int b = blockIdx.x, t = threadIdx.x;
    const int v = (t < NCHUNK) ? chunk_hist[t * NBKT + b] : 0;
    sh[t] = v;
    __syncthreads();
    for (int off = 1; off < 256; off <<= 1) {
        int add = (t >= off) ? sh[t - off] : 0;
        __syncthreads();
        sh[t] += add;
        __syncthreads();
    }
    if (t < NCHUNK) chunk_base[t * NBKT + b] = sh[t] - v;   // exclusive
    if (t == 255) btotal[b] = sh[255];
}

// ---------------- cross-bucket exclusive scan + attn->f16 ----------------
__global__ __launch_bounds__(256) void scan_buckets_k(
    const int* __restrict__ btotal, int* __restrict__ bkbase,
    const float* __restrict__ attn, __half* __restrict__ attn_h)
{
    __shared__ int sh[256];
    const int t = threadIdx.x;
    const int v = (t < NBKT) ? btotal[t] : 0;
    sh[t] = v;
    __syncthreads();
    for (int off = 1; off < 256; off <<= 1) {
        int add = (t >= off) ? sh[t - off] : 0;
        __syncthreads();
        sh[t] += add;
        __syncthreads();
    }
    if (t < NBKT) bkbase[t] = sh[t] - v;     // exclusive
    if (t == 0) bkbase[NBKT] = NE;
    if (t < FOUT) attn_h[t] = __float2half(attn[t]);
}

// ---------------- FUSED: MFMA GEMM (x staged ONCE; inner loop over 4 col-tiles) + scatter ----------------
// b % 3 == 0 -> scatter chunk b/3 (196); else gemm stripe g = b - b/3 - 1 (391 used)
// LDS: As 32KB + Bs 16KB = 48KB -> 3 blocks/CU (occupancy fix for round-13's 96KB/1-block cliff)
__global__ __launch_bounds__(256) void gemm_scatter_k(
    const float* __restrict__ x, const ushort* __restrict__ Wt,
    const float* __restrict__ bsrc, const float* __restrict__ bdst,
    __half* __restrict__ fsfd,
    const int* __restrict__ dst, const int* __restrict__ src,
    const int* __restrict__ bkbase, const int* __restrict__ chunk_base,
    uint* __restrict__ ebuf)
{
    __shared__ ushort As[128 * 128];   // 32 KB
    __shared__ ushort Bs[64 * 128];    // 16 KB (one 64-col tile of Wt)
    __shared__ int cur[NBKT];
    const int b = blockIdx.x;
    const int tid = threadIdx.x;

    if (b % 3 == 0) {
        // ---- scatter role: positions precomputed, LDS cursors only ----
        const int chunk = b / 3;
        for (int t = tid; t < NBKT; t += 256)
            cur[t] = bkbase[t] + chunk_base[chunk * NBKT + t];
        __syncthreads();
        const int e0 = chunk * CHUNK;
        #pragma unroll
        for (int k = 0; k < 16; ++k) {
            const int e = e0 + k * 256 + tid;
            if (e < NE) {
                const int d = dst[e];
                const int p = atomicAdd(&cur[d >> 9], 1);   // LDS atomic
                ebuf[p] = ((uint)d << 16) | (uint)src[e];
            }
        }
        return;
    }

    // ---- gemm role: one 128-row stripe; x staged ONCE; loop over 4 column tiles ----
    const int g = b - b / 3 - 1;
    if (g >= N_GEMM) return;
    const int bm = g * 128;

    // A tile: read f32 x ONCE, convert to bf16 in-register, swizzled LDS write
    for (int q = tid; q < 128 * 16; q += 256) {
        int r = q >> 4, c16 = q & 15;
        int row = bm + r;
        uint4 o = make_uint4(0u, 0u, 0u, 0u);
        if (row < NN) {
            const float4 a = *(const float4*)&x[(size_t)row * FIN + c16 * 8];
            const float4 c = *(const float4*)&x[(size_t)row * FIN + c16 * 8 + 4];
            o.x = f2bf_u(a.x) | (f2bf_u(a.y) << 16);
            o.y = f2bf_u(a.z) | (f2bf_u(a.w) << 16);
            o.z = f2bf_u(c.x) | (f2bf_u(c.y) << 16);
            o.w = f2bf_u(c.z) | (f2bf_u(c.w) << 16);
        }
        int off = r * 256 + ((c16 * 16) ^ ((r & 7) << 4));
        *(uint4*)((char*)As + off) = o;
    }

    const int wid = tid >> 6, lane = tid & 63;
    const int wr = (wid >> 1) * 64, wc = (wid & 1) * 32;
    const int lrow = lane & 15;
    const int lk = (lane >> 4) * 16;

    #pragma unroll
    for (int ct = 0; ct < 4; ++ct) {
        if (ct > 0) __syncthreads();   // all waves done reading previous Bs
        // stage this column tile of Wt (rows ct*64 .. ct*64+63)
        for (int q = tid; q < 64 * 16; q += 256) {
            int r = q >> 4, c16 = q & 15;
            uint4 v = *(const uint4*)&Wt[(ct * 64 + r) * FIN + c16 * 8];
            int off = r * 256 + ((c16 * 16) ^ ((r & 7) << 4));
            *(uint4*)((char*)Bs + off) = v;
        }
        __syncthreads();

        f32x4 acc[4][2] = {};
        #pragma unroll
        for (int kk = 0; kk < 4; ++kk) {
            bf16x8 a[4], bb[2];
            #pragma unroll
            for (int m = 0; m < 4; ++m) {
                int r = wr + m * 16 + lrow;
                int off = r * 256 + ((kk * 64 + lk) ^ ((r & 7) << 4));
                a[m] = *(bf16x8*)((char*)As + off);
            }
            #pragma unroll
            for (int n = 0; n < 2; ++n) {
                int r = wc + n * 16 + lrow;
                int off = r * 256 + ((kk * 64 + lk) ^ ((r & 7) << 4));
                bb[n] = *(bf16x8*)((char*)Bs + off);
            }
            #pragma unroll
            for (int m = 0; m < 4; ++m)
                #pragma unroll
                for (int n = 0; n < 2; ++n)
                    acc[m][n] = __builtin_amdgcn_mfma_f32_16x16x32_bf16(a[m], bb[n], acc[m][n], 0, 0, 0);
        }

        #pragma unroll
        for (int m = 0; m < 4; ++m) {
            #pragma unroll
            for (int n = 0; n < 2; ++n) {
                int gcol = ct * 64 + wc + n * 16 + (lane & 15);
                float bias = (gcol < 128) ? bsrc[gcol] : bdst[gcol - 128];
                #pragma unroll
                for (int r = 0; r < 4; ++r) {
                    int grow = bm + wr + m * 16 + (lane >> 4) * 4 + r;
                    if (grow < NN)
                        fsfd[(size_t)grow * 256 + gcol] = __float2half(acc[m][n][r] + bias);
                }
            }
        }
    }
}

// ---------------- binB: per-bucket rowptr build (LDS) + coalesced nbr ----------------
__global__ __launch_bounds__(256) void binB_k(
    const uint* __restrict__ ebuf, const int* __restrict__ bkbase,
    int* __restrict__ rowptr, ushort* __restrict__ nbr)
{
    __shared__ int cnt_s[512];
    __shared__ int ps[256];
    __shared__ ushort buf[BCAP];
    const int b = blockIdx.x;
    const int tid = threadIdx.x;
    const int node0 = b << 9;
    const int nodes = (node0 + 512 < NN) ? 512 : (NN - node0);
    const int segbase = bkbase[b];
    const int segend  = bkbase[b + 1];
    const int seglen  = segend - segbase;

    cnt_s[tid] = 0;
    cnt_s[tid + 256] = 0;
    __syncthreads();
    for (int i = segbase + tid; i < segend; i += 256)
        atomicAdd(&cnt_s[(int)(ebuf[i] >> 16) - node0], 1);   // LDS atomic
    __syncthreads();

    // 512-wide exclusive prefix scan (2 elems/thread)
    const int c0 = cnt_s[2 * tid], c1 = cnt_s[2 * tid + 1];
    const int pair = c0 + c1;
    ps[tid] = pair;
    __syncthreads();
    for (int off = 1; off < 256; off <<= 1) {
        int add = (tid >= off) ? ps[tid - off] : 0;
        __syncthreads();
        ps[tid] += add;
        __syncthreads();
    }
    const int ex = ps[tid] - pair;
    __syncthreads();
    cnt_s[2 * tid] = ex;
    cnt_s[2 * tid + 1] = ex + c0;
    if (2 * tid < nodes)     rowptr[node0 + 2 * tid]     = segbase + ex;
    if (2 * tid + 1 < nodes) rowptr[node0 + 2 * tid + 1] = segbase + ex + c0;
    if (b == NBKT - 1 && tid == 0) rowptr[NN] = segend;
    __syncthreads();

    if (seglen <= BCAP) {
        for (int i = segbase + tid; i < segend; i += 256) {
            const uint e = ebuf[i];
            const int d = (int)(e >> 16) - node0;
            const int p = atomicAdd(&cnt_s[d], 1);
            buf[p] = (ushort)(e & 0xffffu);
        }
        __syncthreads();
        for (int i = tid; i < seglen; i += 256)
            nbr[segbase + i] = buf[i];
    } else {
        // correctness fallback: direct (uncoalesced) global writes
        for (int i = segbase + tid; i < segend; i += 256) {
            const uint e = ebuf[i];
            const int d = (int)(e >> 16) - node0;
            const int p = atomicAdd(&cnt_s[d], 1);
            nbr[segbase + p] = (ushort)(e & 0xffffu);
        }
    }
}

// ---------------- Fused per-node GAT kernel (packed f16, 4 gathers in flight) ----------------
// One wave per node. ql = lane&15 owns elems {8ql..8ql+7} (4 half2); quarter-waves
// process 4 edges concurrently; i-step 16 keeps 4 row-gathers in flight per quarter.
__global__ __launch_bounds__(256) void gat_node_k(
    const __half* __restrict__ fsfd, const __half* __restrict__ attn_h,
    const int* __restrict__ rowptr, const ushort* __restrict__ nbr,
    float* __restrict__ out)
{
    const int node = blockIdx.x * 4 + (threadIdx.x >> 6);
    const int lane = threadIdx.x & 63;
    const int ql = lane & 15;
    const int q  = lane >> 4;

    const uint4 ufd = *(const uint4*)&fsfd[(size_t)node * 256 + 128 + 8 * ql];
    const __half2 fd0 = u2h(ufd.x), fd1 = u2h(ufd.y), fd2 = u2h(ufd.z), fd3 = u2h(ufd.w);
    const uint4 uav = *(const uint4*)&attn_h[8 * ql];
    const __half2 av0 = u2h(uav.x), av1 = u2h(uav.y), av2 = u2h(uav.z), av3 = u2h(uav.w);
    const __half2 k02 = __float2half2_rn(NEG);

    const int beg = rowptr[node];
    const int end = rowptr[node + 1];

    float den = 0.f;
    __half2 acc0 = u2h(0), acc1 = u2h(0), acc2 = u2h(0), acc3 = u2h(0);

    for (int i = beg; i < end; i += 16) {
        #pragma unroll
        for (int j = 0; j < 4; ++j) {
            const int idx = i + 4 * j + q;
            const bool valid = idx < end;
            const int s = nbr[valid ? idx : end - 1];
            const uint4 u = *(const uint4*)&fsfd[(size_t)s * 256 + 8 * ql];
            const __half2 f0 = u2h(u.x), f1 = u2h(u.y), f2 = u2h(u.z), f3 = u2h(u.w);
            __half2 v0 = __hadd2(f0, fd0), v1 = __hadd2(f1, fd1);
            __half2 v2 = __hadd2(f2, fd2), v3 = __hadd2(f3, fd3);
            v0 = hmax2(v0, __hmul2(v0, k02));
            v1 = hmax2(v1, __hmul2(v1, k02));
            v2 = hmax2(v2, __hmul2(v2, k02));
            v3 = hmax2(v3, __hmul2(v3, k02));
            __half2 sch = __hmul2(v0, av0);
            sch = __hfma2(v1, av1, sch);
            sch = __hfma2(v2, av2, sch);
            sch = __hfma2(v3, av3, sch);
            float sc = __low2float(sch) + __high2float(sch);
            sc = dpp_add<DPP_QUAD_XOR1>(sc);
            sc = dpp_add<DPP_QUAD_XOR2>(sc);
            float ex = __expf(sc);
            ex = valid ? ex : 0.f;
            den += ex;
            const __half2 exh = __float2half2_rn(ex);
            acc0 = __hfma2(exh, f0, acc0);
            acc1 = __hfma2(exh, f1, acc1);
            acc2 = __hfma2(exh, f2, acc2);
            acc3 = __hfma2(exh, f3, acc3);
        }
    }

    den += __shfl_xor(den, 16, 64);
    den += __shfl_xor(den, 32, 64);
    uint ua0 = h2u(acc0), ua1 = h2u(acc1), ua2 = h2u(acc2), ua3 = h2u(acc3);
    ua0 = h2u(__hadd2(u2h(ua0), u2h((uint)__shfl_xor((int)ua0, 16, 64))));
    ua1 = h2u(__hadd2(u2h(ua1), u2h((uint)__shfl_xor((int)ua1, 16, 64))));
    ua2 = h2u(__hadd2(u2h(ua2), u2h((uint)__shfl_xor((int)ua2, 16, 64))));
    ua3 = h2u(__hadd2(u2h(ua3), u2h((uint)__shfl_xor((int)ua3, 16, 64))));
    ua0 = h2u(__hadd2(u2h(ua0), u2h((uint)__shfl_xor((int)ua0, 32, 64))));
    ua1 = h2u(__hadd2(u2h(ua1), u2h((uint)__shfl_xor((int)ua1, 32, 64))));
    ua2 = h2u(__hadd2(u2h(ua2), u2h((uint)__shfl_xor((int)ua2, 32, 64))));
    ua3 = h2u(__hadd2(u2h(ua3), u2h((uint)__shfl_xor((int)ua3, 32, 64))));

    if (q == 0) {
        const float inv = (den > 0.f) ? 1.f / den : 0.f;
        float4 o0, o1;
        o0.x = fmaxf(__low2float(u2h(ua0))  * inv, 0.f);
        o0.y = fmaxf(__high2float(u2h(ua0)) * inv, 0.f);
        o0.z = fmaxf(__low2float(u2h(ua1))  * inv, 0.f);
        o0.w = fmaxf(__high2float(u2h(ua1)) * inv, 0.f);
        o1.x = fmaxf(__low2float(u2h(ua2))  * inv, 0.f);
        o1.y = fmaxf(__high2float(u2h(ua2)) * inv, 0.f);
        o1.z = fmaxf(__low2float(u2h(ua3))  * inv, 0.f);
        o1.w = fmaxf(__high2float(u2h(ua3)) * inv, 0.f);
        *(float4*)&out[(size_t)node * FOUT + 8 * ql] = o0;
        *(float4*)&out[(size_t)node * FOUT + 8 * ql + 4] = o1;
    }
}

extern "C" void kernel_launch(void* const* d_in, const int* in_sizes, int n_in,
                              void* d_out, int out_size, void* d_ws, size_t ws_size,
                              hipStream_t stream)
{
    const float* x    = (const float*)d_in[0];
    const int*   src  = (const int*)d_in[1];
    const int*   dst  = (const int*)d_in[2];
    const float* Wsrc = (const float*)d_in[3];
    const float* bsrc = (const float*)d_in[4];
    const float* Wdst = (const float*)d_in[5];
    const float* bdst = (const float*)d_in[6];
    const float* attn = (const float*)d_in[7];
    float* out = (float*)d_out;

    ushort* Wt      = (ushort*)d_ws;                      // 256*128 bf16
    __half* fsfd    = (__half*)(Wt + 256 * FIN);          // NN*256 f16
    int* chunk_hist = (int*)(fsfd + (size_t)NN * 256);    // NCHUNK*NBKT
    int* chunk_base = chunk_hist + NCHUNK * NBKT;         // NCHUNK*NBKT
    int* btotal     = chunk_base + NCHUNK * NBKT;         // NBKT
    int* bkbase     = btotal + NBKT;                      // NBKT+1
    int* rowptr     = bkbase + NBKT + 1;                  // NN+1
    uint* ebuf      = (uint*)(rowptr + NN + 1);           // NE packed (d<<16)|s
    ushort* nbr     = (ushort*)(ebuf + NE);               // NE u16
    __half* attn_h  = (__half*)(nbr + NE);                // 128 f16

    hist_wt_k<<<NCHUNK + NB_W, 256, 0, stream>>>(dst, chunk_hist, Wsrc, Wdst, Wt);
    scan_chunks_k<<<NBKT, 256, 0, stream>>>(chunk_hist, chunk_base, btotal);
    scan_buckets_k<<<1, 256, 0, stream>>>(btotal, bkbase, attn, attn_h);
    gemm_scatter_k<<<GB_GRID, 256, 0, stream>>>(x, Wt, bsrc, bdst, fsfd,
                                                dst, src, bkbase, chunk_base, ebuf);
    binB_k<<<NBKT, 256, 0, stream>>>(ebuf, bkbase, rowptr, nbr);
    gat_node_k<<<(NN + 3) / 4, 256, 0, stream>>>(fsfd, attn_h, rowptr, nbr, out);
}

// Round 15
// 89.454 us; speedup vs baseline: 1.1941x; 1.0216x over previous
//
#include <hip/hip_runtime.h>
#include <hip/hip_fp16.h>

#define NN 50000
#define NE 800000
#define FIN 128
#define NH 4
#define HD 32
#define FOUT 128   // NH*HD
#define NEG 0.2f
#define NB_W    ((256 * FIN + 255) / 256) // 128
#define N_GEMM  391                  // 128-row stripes; each block does all 4 col-tiles
#define NBKT    98                   // dst>>9 buckets (512 nodes each)
#define CHUNK   4096                 // edges per hist/scatter chunk
#define NCHUNK  ((NE + CHUNK - 1) / CHUNK)  // 196
#define GB_GRID (NCHUNK * 3)         // 588: b%3==0 -> scatter (196), else gemm (391 used)
#define BCAP    12288                // binB LDS segment capacity (mean 8163, max ~8600)

typedef __attribute__((ext_vector_type(8))) short bf16x8;
typedef __attribute__((ext_vector_type(4))) float f32x4;

__device__ __forceinline__ uint f2bf_u(float f) {
    uint u = __float_as_uint(f);
    u += 0x7FFF + ((u >> 16) & 1);   // round-to-nearest-even
    return u >> 16;
}
__device__ __forceinline__ ushort f2bf(float f) { return (ushort)f2bf_u(f); }

template<int CTRL>
__device__ __forceinline__ float dpp_add(float x) {
    int y = __builtin_amdgcn_update_dpp(0, __float_as_int(x), CTRL, 0xF, 0xF, false);
    return x + __int_as_float(y);
}
#define DPP_QUAD_XOR1 0xB1   // quad_perm [1,0,3,2]
#define DPP_QUAD_XOR2 0x4E   // quad_perm [2,3,0,1]

__device__ __forceinline__ __half2 u2h(uint u) { return __builtin_bit_cast(__half2, u); }
__device__ __forceinline__ uint h2u(__half2 h) { return __builtin_bit_cast(uint, h); }

// ROCm 7.2 hip_fp16.h lacks __hmax2 — emit v_pk_max_f16 directly
__device__ __forceinline__ __half2 hmax2(__half2 a, __half2 b) {
    uint r, ua = h2u(a), ub = h2u(b);
    asm("v_pk_max_f16 %0, %1, %2" : "=v"(r) : "v"(ua), "v"(ub));
    return u2h(r);
}

// ---------------- hist chunks + Wt conversion + attn->f16 (one launch) ----------------
__global__ __launch_bounds__(256) void hist_wt_k(
    const int* __restrict__ dst, int* __restrict__ chunk_hist,
    const float* __restrict__ Wsrc, const float* __restrict__ Wdst,
    ushort* __restrict__ Wt,
    const float* __restrict__ attn, __half* __restrict__ attn_h)
{
    __shared__ int hist[NBKT];
    const int b = blockIdx.x;
    const int tid = threadIdx.x;
    if (b < NCHUNK) {
        const int e0 = b * CHUNK;
        for (int t = tid; t < NBKT; t += 256) hist[t] = 0;
        __syncthreads();
        #pragma unroll
        for (int k = 0; k < 16; ++k) {
            const int e = e0 + k * 256 + tid;
            if (e < NE) atomicAdd(&hist[dst[e] >> 9], 1);
        }
        __syncthreads();
        for (int t = tid; t < NBKT; t += 256)
            chunk_hist[b * NBKT + t] = hist[t];
    } else {
        if (b == NCHUNK && tid < FOUT) attn_h[tid] = __float2half(attn[tid]);
        int t = (b - NCHUNK) * 256 + tid;
        if (t >= 256 * FIN) return;
        int n = t >> 7, k = t & 127;
        float v = (n < 128) ? Wsrc[k * 128 + n] : Wdst[k * 128 + (n - 128)];
        Wt[t] = f2bf(v);
    }
}

// ---------------- FUSED: MFMA GEMM (x staged ONCE; 4 col-tiles) + scatter w/ inline scan ----------------
// b % 3 == 0 -> scatter chunk b/3 (196, each recomputes the bucket scan locally — no scan kernels);
// else gemm stripe g = b - b/3 - 1 (391 used).
// LDS: As 32KB + Bs 16KB (+ ~1.5KB scan) -> 3 blocks/CU
__global__ __launch_bounds__(256) void gemm_scatter_k(
    const float* __restrict__ x, const ushort* __restrict__ Wt,
    const float* __restrict__ bsrc, const float* __restrict__ bdst,
    __half* __restrict__ fsfd,
    const int* __restrict__ dst, const int* __restrict__ src,
    const int* __restrict__ chunk_hist, int* __restrict__ bkbase,
    uint* __restrict__ ebuf)
{
    __shared__ ushort As[128 * 128];   // 32 KB
    __shared__ ushort Bs[64 * 128];    // 16 KB (one 64-col tile of Wt)
    __shared__ int cur[NBKT];
    __shared__ int ps[256];
    const int b = blockIdx.x;
    const int tid = threadIdx.x;

    if (b % 3 == 0) {
        // ---- scatter role: recompute bucket scan from chunk_hist (L2-resident, 77KB) ----
        const int chunk = b / 3;
        int total = 0, part = 0;
        if (tid < NBKT) {
            for (int c = 0; c < NCHUNK; ++c) {          // coalesced: threads 0..97 read row c
                const int h = chunk_hist[c * NBKT + tid];
                total += h;
                part += (c < chunk) ? h : 0;
            }
        }
        ps[tid] = (tid < NBKT) ? total : 0;
        __syncthreads();
        for (int off = 1; off < 256; off <<= 1) {
            int add = (tid >= off) ? ps[tid - off] : 0;
            __syncthreads();
            ps[tid] += add;
            __syncthreads();
        }
        if (tid < NBKT) cur[tid] = (ps[tid] - total) + part;   // bkbase[t] + partial
        if (chunk == 0) {                                      // publish bkbase for binB
            if (tid < NBKT) bkbase[tid] = ps[tid] - total;
            if (tid == 0) bkbase[NBKT] = NE;
        }
        __syncthreads();
        const int e0 = chunk * CHUNK;
        #pragma unroll
        for (int k = 0; k < 16; ++k) {
            const int e = e0 + k * 256 + tid;
            if (e < NE) {
                const int d = dst[e];
                const int p = atomicAdd(&cur[d >> 9], 1);   // LDS atomic
                ebuf[p] = ((uint)d << 16) | (uint)src[e];
            }
        }
        return;
    }

    // ---- gemm role: one 128-row stripe; x staged ONCE; loop over 4 column tiles ----
    const int g = b - b / 3 - 1;
    if (g >= N_GEMM) return;
    const int bm = g * 128;

    // A tile: read f32 x ONCE, convert to bf16 in-register, swizzled LDS write
    for (int q = tid; q < 128 * 16; q += 256) {
        int r = q >> 4, c16 = q & 15;
        int row = bm + r;
        uint4 o = make_uint4(0u, 0u, 0u, 0u);
        if (row < NN) {
            const float4 a = *(const float4*)&x[(size_t)row * FIN + c16 * 8];
            const float4 c = *(const float4*)&x[(size_t)row * FIN + c16 * 8 + 4];
            o.x = f2bf_u(a.x) | (f2bf_u(a.y) << 16);
            o.y = f2bf_u(a.z) | (f2bf_u(a.w) << 16);
            o.z = f2bf_u(c.x) | (f2bf_u(c.y) << 16);
            o.w = f2bf_u(c.z) | (f2bf_u(c.w) << 16);
        }
        int off = r * 256 + ((c16 * 16) ^ ((r & 7) << 4));
        *(uint4*)((char*)As + off) = o;
    }

    const int wid = tid >> 6, lane = tid & 63;
    const int wr = (wid >> 1) * 64, wc = (wid & 1) * 32;
    const int lrow = lane & 15;
    const int lk = (lane >> 4) * 16;

    #pragma unroll
    for (int ct = 0; ct < 4; ++ct) {
        if (ct > 0) __syncthreads();   // all waves done reading previous Bs
        for (int q = tid; q < 64 * 16; q += 256) {
            int r = q >> 4, c16 = q & 15;
            uint4 v = *(const uint4*)&Wt[(ct * 64 + r) * FIN + c16 * 8];
            int off = r * 256 + ((c16 * 16) ^ ((r & 7) << 4));
            *(uint4*)((char*)Bs + off) = v;
        }
        __syncthreads();

        f32x4 acc[4][2] = {};
        #pragma unroll
        for (int kk = 0; kk < 4; ++kk) {
            bf16x8 a[4], bb[2];
            #pragma unroll
            for (int m = 0; m < 4; ++m) {
                int r = wr + m * 16 + lrow;
                int off = r * 256 + ((kk * 64 + lk) ^ ((r & 7) << 4));
                a[m] = *(bf16x8*)((char*)As + off);
            }
            #pragma unroll
            for (int n = 0; n < 2; ++n) {
                int r = wc + n * 16 + lrow;
                int off = r * 256 + ((kk * 64 + lk) ^ ((r & 7) << 4));
                bb[n] = *(bf16x8*)((char*)Bs + off);
            }
            #pragma unroll
            for (int m = 0; m < 4; ++m)
                #pragma unroll
                for (int n = 0; n < 2; ++n)
                    acc[m][n] = __builtin_amdgcn_mfma_f32_16x16x32_bf16(a[m], bb[n], acc[m][n], 0, 0, 0);
        }

        #pragma unroll
        for (int m = 0; m < 4; ++m) {
            #pragma unroll
            for (int n = 0; n < 2; ++n) {
                int gcol = ct * 64 + wc + n * 16 + (lane & 15);
                float bias = (gcol < 128) ? bsrc[gcol] : bdst[gcol - 128];
                #pragma unroll
                for (int r = 0; r < 4; ++r) {
                    int grow = bm + wr + m * 16 + (lane >> 4) * 4 + r;
                    if (grow < NN)
                        fsfd[(size_t)grow * 256 + gcol] = __float2half(acc[m][n][r] + bias);
                }
            }
        }
    }
}

// ---------------- binB: per-bucket rowptr build (LDS) + coalesced nbr ----------------
__global__ __launch_bounds__(256) void binB_k(
    const uint* __restrict__ ebuf, const int* __restrict__ bkbase,
    int* __restrict__ rowptr, ushort* __restrict__ nbr)
{
    __shared__ int cnt_s[512];
    __shared__ int ps[256];
    __shared__ ushort buf[BCAP];
    const int b = blockIdx.x;
    const int tid = threadIdx.x;
    const int node0 = b << 9;
    const int nodes = (node0 + 512 < NN) ? 512 : (NN - node0);
    const int segbase = bkbase[b];
    const int segend  = bkbase[b + 1];
    const int seglen  = segend - segbase;

    cnt_s[tid] = 0;
    cnt_s[tid + 256] = 0;
    __syncthreads();
    for (int i = segbase + tid; i < segend; i += 256)
        atomicAdd(&cnt_s[(int)(ebuf[i] >> 16) - node0], 1);   // LDS atomic
    __syncthreads();

    // 512-wide exclusive prefix scan (2 elems/thread)
    const int c0 = cnt_s[2 * tid], c1 = cnt_s[2 * tid + 1];
    const int pair = c0 + c1;
    ps[tid] = pair;
    __syncthreads();
    for (int off = 1; off < 256; off <<= 1) {
        int add = (tid >= off) ? ps[tid - off] : 0;
        __syncthreads();
        ps[tid] += add;
        __syncthreads();
    }
    const int ex = ps[tid] - pair;
    __syncthreads();
    cnt_s[2 * tid] = ex;
    cnt_s[2 * tid + 1] = ex + c0;
    if (2 * tid < nodes)     rowptr[node0 + 2 * tid]     = segbase + ex;
    if (2 * tid + 1 < nodes) rowptr[node0 + 2 * tid + 1] = segbase + ex + c0;
    if (b == NBKT - 1 && tid == 0) rowptr[NN] = segend;
    __syncthreads();

    if (seglen <= BCAP) {
        for (int i = segbase + tid; i < segend; i += 256) {
            const uint e = ebuf[i];
            const int d = (int)(e >> 16) - node0;
            const int p = atomicAdd(&cnt_s[d], 1);
            buf[p] = (ushort)(e & 0xffffu);
        }
        __syncthreads();
        for (int i = tid; i < seglen; i += 256)
            nbr[segbase + i] = buf[i];
    } else {
        // correctness fallback: direct (uncoalesced) global writes
        for (int i = segbase + tid; i < segend; i += 256) {
            const uint e = ebuf[i];
            const int d = (int)(e >> 16) - node0;
            const int p = atomicAdd(&cnt_s[d], 1);
            nbr[segbase + p] = (ushort)(e & 0xffffu);
        }
    }
}

// ---------------- Fused per-node GAT kernel (packed f16, 4 gathers in flight) ----------------
// One wave per node. ql = lane&15 owns elems {8ql..8ql+7} (4 half2); quarter-waves
// process 4 edges concurrently; i-step 16 keeps 4 row-gathers in flight per quarter.
__global__ __launch_bounds__(256) void gat_node_k(
    const __half* __restrict__ fsfd, const __half* __restrict__ attn_h,
    const int* __restrict__ rowptr, const ushort* __restrict__ nbr,
    float* __restrict__ out)
{
    const int node = blockIdx.x * 4 + (threadIdx.x >> 6);
    const int lane = threadIdx.x & 63;
    const int ql = lane & 15;
    const int q  = lane >> 4;

    const uint4 ufd = *(const uint4*)&fsfd[(size_t)node * 256 + 128 + 8 * ql];
    const __half2 fd0 = u2h(ufd.x), fd1 = u2h(ufd.y), fd2 = u2h(ufd.z), fd3 = u2h(ufd.w);
    const uint4 uav = *(const uint4*)&attn_h[8 * ql];
    const __half2 av0 = u2h(uav.x), av1 = u2h(uav.y), av2 = u2h(uav.z), av3 = u2h(uav.w);
    const __half2 k02 = __float2half2_rn(NEG);

    const int beg = rowptr[node];
    const int end = rowptr[node + 1];

    float den = 0.f;
    __half2 acc0 = u2h(0), acc1 = u2h(0), acc2 = u2h(0), acc3 = u2h(0);

    for (int i = beg; i < end; i += 16) {
        #pragma unroll
        for (int j = 0; j < 4; ++j) {
            const int idx = i + 4 * j + q;
            const bool valid = idx < end;
            const int s = nbr[valid ? idx : end - 1];
            const uint4 u = *(const uint4*)&fsfd[(size_t)s * 256 + 8 * ql];
            const __half2 f0 = u2h(u.x), f1 = u2h(u.y), f2 = u2h(u.z), f3 = u2h(u.w);
            __half2 v0 = __hadd2(f0, fd0), v1 = __hadd2(f1, fd1);
            __half2 v2 = __hadd2(f2, fd2), v3 = __hadd2(f3, fd3);
            v0 = hmax2(v0, __hmul2(v0, k02));
            v1 = hmax2(v1, __hmul2(v1, k02));
            v2 = hmax2(v2, __hmul2(v2, k02));
            v3 = hmax2(v3, __hmul2(v3, k02));
            __half2 sch = __hmul2(v0, av0);
            sch = __hfma2(v1, av1, sch);
            sch = __hfma2(v2, av2, sch);
            sch = __hfma2(v3, av3, sch);
            float sc = __low2float(sch) + __high2float(sch);
            sc = dpp_add<DPP_QUAD_XOR1>(sc);
            sc = dpp_add<DPP_QUAD_XOR2>(sc);
            float ex = __expf(sc);
            ex = valid ? ex : 0.f;
            den += ex;
            const __half2 exh = __float2half2_rn(ex);
            acc0 = __hfma2(exh, f0, acc0);
            acc1 = __hfma2(exh, f1, acc1);
            acc2 = __hfma2(exh, f2, acc2);
            acc3 = __hfma2(exh, f3, acc3);
        }
    }

    den += __shfl_xor(den, 16, 64);
    den += __shfl_xor(den, 32, 64);
    uint ua0 = h2u(acc0), ua1 = h2u(acc1), ua2 = h2u(acc2), ua3 = h2u(acc3);
    ua0 = h2u(__hadd2(u2h(ua0), u2h((uint)__shfl_xor((int)ua0, 16, 64))));
    ua1 = h2u(__hadd2(u2h(ua1), u2h((uint)__shfl_xor((int)ua1, 16, 64))));
    ua2 = h2u(__hadd2(u2h(ua2), u2h((uint)__shfl_xor((int)ua2, 16, 64))));
    ua3 = h2u(__hadd2(u2h(ua3), u2h((uint)__shfl_xor((int)ua3, 16, 64))));
    ua0 = h2u(__hadd2(u2h(ua0), u2h((uint)__shfl_xor((int)ua0, 32, 64))));
    ua1 = h2u(__hadd2(u2h(ua1), u2h((uint)__shfl_xor((int)ua1, 32, 64))));
    ua2 = h2u(__hadd2(u2h(ua2), u2h((uint)__shfl_xor((int)ua2, 32, 64))));
    ua3 = h2u(__hadd2(u2h(ua3), u2h((uint)__shfl_xor((int)ua3, 32, 64))));

    if (q == 0) {
        const float inv = (den > 0.f) ? 1.f / den : 0.f;
        float4 o0, o1;
        o0.x = fmaxf(__low2float(u2h(ua0))  * inv, 0.f);
        o0.y = fmaxf(__high2float(u2h(ua0)) * inv, 0.f);
        o0.z = fmaxf(__low2float(u2h(ua1))  * inv, 0.f);
        o0.w = fmaxf(__high2float(u2h(ua1)) * inv, 0.f);
        o1.x = fmaxf(__low2float(u2h(ua2))  * inv, 0.f);
        o1.y = fmaxf(__high2float(u2h(ua2)) * inv, 0.f);
        o1.z = fmaxf(__low2float(u2h(ua3))  * inv, 0.f);
        o1.w = fmaxf(__high2float(u2h(ua3)) * inv, 0.f);
        *(float4*)&out[(size_t)node * FOUT + 8 * ql] = o0;
        *(float4*)&out[(size_t)node * FOUT + 8 * ql + 4] = o1;
    }
}

extern "C" void kernel_launch(void* const* d_in, const int* in_sizes, int n_in,
                              void* d_out, int out_size, void* d_ws, size_t ws_size,
                              hipStream_t stream)
{
    const float* x    = (const float*)d_in[0];
    const int*   src  = (const int*)d_in[1];
    const int*   dst  = (const int*)d_in[2];
    const float* Wsrc = (const float*)d_in[3];
    const float* bsrc = (const float*)d_in[4];
    const float* Wdst = (const float*)d_in[5];
    const float* bdst = (const float*)d_in[6];
    const float* attn = (const float*)d_in[7];
    float* out = (float*)d_out;

    ushort* Wt      = (ushort*)d_ws;                      // 256*128 bf16
    __half* fsfd    = (__half*)(Wt + 256 * FIN);          // NN*256 f16
    int* chunk_hist = (int*)(fsfd + (size_t)NN * 256);    // NCHUNK*NBKT
    int* bkbase     = chunk_hist + NCHUNK * NBKT;         // NBKT+1
    int* rowptr     = bkbase + NBKT + 1;                  // NN+1
    uint* ebuf      = (uint*)(rowptr + NN + 1);           // NE packed (d<<16)|s
    ushort* nbr     = (ushort*)(ebuf + NE);               // NE u16
    __half* attn_h  = (__half*)(nbr + NE);                // 128 f16

    hist_wt_k<<<NCHUNK + NB_W, 256, 0, stream>>>(dst, chunk_hist, Wsrc, Wdst, Wt, attn, attn_h);
    gemm_scatter_k<<<GB_GRID, 256, 0, stream>>>(x, Wt, bsrc, bdst, fsfd,
                                                dst, src, chunk_hist, bkbase, ebuf);
    binB_k<<<NBKT, 256, 0, stream>>>(ebuf, bkbase, rowptr, nbr);
    gat_node_k<<<(NN + 3) / 4, 256, 0, stream>>>(fsfd, attn_h, rowptr, nbr, out);
}

// Round 16
// 88.957 us; speedup vs baseline: 1.2008x; 1.0056x over previous
//
#include <hip/hip_runtime.h>
#include <hip/hip_fp16.h>

#define NN 50000
#define NE 800000
#define FIN 128
#define NH 4
#define HD 32
#define FOUT 128   // NH*HD
#define NEG 0.2f
#define NB_W    ((256 * FIN + 255) / 256) // 128
#define N_GEMM  782                  // 64-row stripes; each block does all 4 col-tiles
#define NBKT    98                   // dst>>9 buckets (512 nodes each)
#define CHUNK   4096                 // edges per hist/scatter chunk
#define NCHUNK  ((NE + CHUNK - 1) / CHUNK)  // 196
#define GB_GRID 980                  // b%5==0 -> scatter (196), else gemm (782 used)
#define BCAP    12288                // binB LDS segment capacity (mean 8163, max ~8600)

typedef __attribute__((ext_vector_type(8))) short bf16x8;
typedef __attribute__((ext_vector_type(4))) float f32x4;

__device__ __forceinline__ uint f2bf_u(float f) {
    uint u = __float_as_uint(f);
    u += 0x7FFF + ((u >> 16) & 1);   // round-to-nearest-even
    return u >> 16;
}
__device__ __forceinline__ ushort f2bf(float f) { return (ushort)f2bf_u(f); }

template<int CTRL>
__device__ __forceinline__ float dpp_add(float x) {
    int y = __builtin_amdgcn_update_dpp(0, __float_as_int(x), CTRL, 0xF, 0xF, false);
    return x + __int_as_float(y);
}
#define DPP_QUAD_XOR1 0xB1   // quad_perm [1,0,3,2]
#define DPP_QUAD_XOR2 0x4E   // quad_perm [2,3,0,1]

__device__ __forceinline__ __half2 u2h(uint u) { return __builtin_bit_cast(__half2, u); }
__device__ __forceinline__ uint h2u(__half2 h) { return __builtin_bit_cast(uint, h); }

// ROCm 7.2 hip_fp16.h lacks __hmax2 — emit v_pk_max_f16 directly
__device__ __forceinline__ __half2 hmax2(__half2 a, __half2 b) {
    uint r, ua = h2u(a), ub = h2u(b);
    asm("v_pk_max_f16 %0, %1, %2" : "=v"(r) : "v"(ua), "v"(ub));
    return u2h(r);
}

// ---------------- hist chunks + Wt conversion + attn->f16 (one launch) ----------------
__global__ __launch_bounds__(256) void hist_wt_k(
    const int* __restrict__ dst, int* __restrict__ chunk_hist,
    const float* __restrict__ Wsrc, const float* __restrict__ Wdst,
    ushort* __restrict__ Wt,
    const float* __restrict__ attn, __half* __restrict__ attn_h)
{
    __shared__ int hist[NBKT];
    const int b = blockIdx.x;
    const int tid = threadIdx.x;
    if (b < NCHUNK) {
        const int e0 = b * CHUNK;
        for (int t = tid; t < NBKT; t += 256) hist[t] = 0;
        __syncthreads();
        #pragma unroll
        for (int k = 0; k < 16; ++k) {
            const int e = e0 + k * 256 + tid;
            if (e < NE) atomicAdd(&hist[dst[e] >> 9], 1);
        }
        __syncthreads();
        for (int t = tid; t < NBKT; t += 256)
            chunk_hist[b * NBKT + t] = hist[t];
    } else {
        if (b == NCHUNK && tid < FOUT) attn_h[tid] = __float2half(attn[tid]);
        int t = (b - NCHUNK) * 256 + tid;
        if (t >= 256 * FIN) return;
        int n = t >> 7, k = t & 127;
        float v = (n < 128) ? Wsrc[k * 128 + n] : Wdst[k * 128 + (n - 128)];
        Wt[t] = f2bf(v);
    }
}

// ---------------- FUSED: MFMA GEMM (BM=64; x staged ONCE; 4 col-tiles) + scatter w/ inline scan ----
// b % 5 == 0 -> scatter chunk b/5 (196, local scan — no scan kernels);
// else gemm stripe g = b - b/5 - 1 (782 used).
// LDS: As 16KB + Bs 16KB (+ ~1.5KB scan) -> 4 blocks/CU, 980 blocks all co-resident
__global__ __launch_bounds__(256) void gemm_scatter_k(
    const float* __restrict__ x, const ushort* __restrict__ Wt,
    const float* __restrict__ bsrc, const float* __restrict__ bdst,
    __half* __restrict__ fsfd,
    const int* __restrict__ dst, const int* __restrict__ src,
    const int* __restrict__ chunk_hist, int* __restrict__ bkbase,
    uint* __restrict__ ebuf)
{
    __shared__ ushort As[64 * 128];    // 16 KB
    __shared__ ushort Bs[64 * 128];    // 16 KB (one 64-col tile of Wt)
    __shared__ int cur[NBKT];
    __shared__ int ps[256];
    const int b = blockIdx.x;
    const int tid = threadIdx.x;

    if (b % 5 == 0) {
        // ---- scatter role: recompute bucket scan from chunk_hist (L2-resident, 77KB) ----
        const int chunk = b / 5;
        int total = 0, part = 0;
        if (tid < NBKT) {
            for (int c = 0; c < NCHUNK; ++c) {          // coalesced: threads 0..97 read row c
                const int h = chunk_hist[c * NBKT + tid];
                total += h;
                part += (c < chunk) ? h : 0;
            }
        }
        ps[tid] = (tid < NBKT) ? total : 0;
        __syncthreads();
        for (int off = 1; off < 256; off <<= 1) {
            int add = (tid >= off) ? ps[tid - off] : 0;
            __syncthreads();
            ps[tid] += add;
            __syncthreads();
        }
        if (tid < NBKT) cur[tid] = (ps[tid] - total) + part;   // bkbase[t] + partial
        if (chunk == 0) {                                      // publish bkbase for binB
            if (tid < NBKT) bkbase[tid] = ps[tid] - total;
            if (tid == 0) bkbase[NBKT] = NE;
        }
        __syncthreads();
        const int e0 = chunk * CHUNK;
        #pragma unroll
        for (int k = 0; k < 16; ++k) {
            const int e = e0 + k * 256 + tid;
            if (e < NE) {
                const int d = dst[e];
                const int p = atomicAdd(&cur[d >> 9], 1);   // LDS atomic
                ebuf[p] = ((uint)d << 16) | (uint)src[e];
            }
        }
        return;
    }

    // ---- gemm role: one 64-row stripe; x staged ONCE; loop over 4 column tiles ----
    const int g = b - b / 5 - 1;
    if (g >= N_GEMM) return;
    const int bm = g * 64;

    // A tile: read f32 x ONCE, convert to bf16 in-register, swizzled LDS write (4 chunks/thread)
    for (int q = tid; q < 64 * 16; q += 256) {
        int r = q >> 4, c16 = q & 15;
        int row = bm + r;
        uint4 o = make_uint4(0u, 0u, 0u, 0u);
        if (row < NN) {
            const float4 a = *(const float4*)&x[(size_t)row * FIN + c16 * 8];
            const float4 c = *(const float4*)&x[(size_t)row * FIN + c16 * 8 + 4];
            o.x = f2bf_u(a.x) | (f2bf_u(a.y) << 16);
            o.y = f2bf_u(a.z) | (f2bf_u(a.w) << 16);
            o.z = f2bf_u(c.x) | (f2bf_u(c.y) << 16);
            o.w = f2bf_u(c.z) | (f2bf_u(c.w) << 16);
        }
        int off = r * 256 + ((c16 * 16) ^ ((r & 7) << 4));
        *(uint4*)((char*)As + off) = o;
    }

    const int wid = tid >> 6, lane = tid & 63;
    const int wr = (wid >> 1) * 32, wc = (wid & 1) * 32;   // 2x2 waves, each 32x32 per ct
    const int lrow = lane & 15;
    const int lk = (lane >> 4) * 16;

    #pragma unroll
    for (int ct = 0; ct < 4; ++ct) {
        if (ct > 0) __syncthreads();   // all waves done reading previous Bs
        for (int q = tid; q < 64 * 16; q += 256) {
            int r = q >> 4, c16 = q & 15;
            uint4 v = *(const uint4*)&Wt[(ct * 64 + r) * FIN + c16 * 8];
            int off = r * 256 + ((c16 * 16) ^ ((r & 7) << 4));
            *(uint4*)((char*)Bs + off) = v;
        }
        __syncthreads();

        f32x4 acc[2][2] = {};
        #pragma unroll
        for (int kk = 0; kk < 4; ++kk) {
            bf16x8 a[2], bb[2];
            #pragma unroll
            for (int m = 0; m < 2; ++m) {
                int r = wr + m * 16 + lrow;
                int off = r * 256 + ((kk * 64 + lk) ^ ((r & 7) << 4));
                a[m] = *(bf16x8*)((char*)As + off);
            }
            #pragma unroll
            for (int n = 0; n < 2; ++n) {
                int r = wc + n * 16 + lrow;
                int off = r * 256 + ((kk * 64 + lk) ^ ((r & 7) << 4));
                bb[n] = *(bf16x8*)((char*)Bs + off);
            }
            #pragma unroll
            for (int m = 0; m < 2; ++m)
                #pragma unroll
                for (int n = 0; n < 2; ++n)
                    acc[m][n] = __builtin_amdgcn_mfma_f32_16x16x32_bf16(a[m], bb[n], acc[m][n], 0, 0, 0);
        }

        #pragma unroll
        for (int m = 0; m < 2; ++m) {
            #pragma unroll
            for (int n = 0; n < 2; ++n) {
                int gcol = ct * 64 + wc + n * 16 + (lane & 15);
                float bias = (gcol < 128) ? bsrc[gcol] : bdst[gcol - 128];
                #pragma unroll
                for (int r = 0; r < 4; ++r) {
                    int grow = bm + wr + m * 16 + (lane >> 4) * 4 + r;
                    if (grow < NN)
                        fsfd[(size_t)grow * 256 + gcol] = __float2half(acc[m][n][r] + bias);
                }
            }
        }
    }
}

// ---------------- binB: per-bucket rowptr build (LDS) + coalesced nbr ----------------
__global__ __launch_bounds__(256) void binB_k(
    const uint* __restrict__ ebuf, const int* __restrict__ bkbase,
    int* __restrict__ rowptr, ushort* __restrict__ nbr)
{
    __shared__ int cnt_s[512];
    __shared__ int ps[256];
    __shared__ ushort buf[BCAP];
    const int b = blockIdx.x;
    const int tid = threadIdx.x;
    const int node0 = b << 9;
    const int nodes = (node0 + 512 < NN) ? 512 : (NN - node0);
    const int segbase = bkbase[b];
    const int segend  = bkbase[b + 1];
    const int seglen  = segend - segbase;

    cnt_s[tid] = 0;
    cnt_s[tid + 256] = 0;
    __syncthreads();
    for (int i = segbase + tid; i < segend; i += 256)
        atomicAdd(&cnt_s[(int)(ebuf[i] >> 16) - node0], 1);   // LDS atomic
    __syncthreads();

    // 512-wide exclusive prefix scan (2 elems/thread)
    const int c0 = cnt_s[2 * tid], c1 = cnt_s[2 * tid + 1];
    const int pair = c0 + c1;
    ps[tid] = pair;
    __syncthreads();
    for (int off = 1; off < 256; off <<= 1) {
        int add = (tid >= off) ? ps[tid - off] : 0;
        __syncthreads();
        ps[tid] += add;
        __syncthreads();
    }
    const int ex = ps[tid] - pair;
    __syncthreads();
    cnt_s[2 * tid] = ex;
    cnt_s[2 * tid + 1] = ex + c0;
    if (2 * tid < nodes)     rowptr[node0 + 2 * tid]     = segbase + ex;
    if (2 * tid + 1 < nodes) rowptr[node0 + 2 * tid + 1] = segbase + ex + c0;
    if (b == NBKT - 1 && tid == 0) rowptr[NN] = segend;
    __syncthreads();

    if (seglen <= BCAP) {
        for (int i = segbase + tid; i < segend; i += 256) {
            const uint e = ebuf[i];
            const int d = (int)(e >> 16) - node0;
            const int p = atomicAdd(&cnt_s[d], 1);
            buf[p] = (ushort)(e & 0xffffu);
        }
        __syncthreads();
        for (int i = tid; i < seglen; i += 256)
            nbr[segbase + i] = buf[i];
    } else {
        // correctness fallback: direct (uncoalesced) global writes
        for (int i = segbase + tid; i < segend; i += 256) {
            const uint e = ebuf[i];
            const int d = (int)(e >> 16) - node0;
            const int p = atomicAdd(&cnt_s[d], 1);
            nbr[segbase + p] = (ushort)(e & 0xffffu);
        }
    }
}

// ---------------- Fused per-node GAT kernel (packed f16, 4 gathers in flight) ----------------
// One wave per node. ql = lane&15 owns elems {8ql..8ql+7} (4 half2); quarter-waves
// process 4 edges concurrently; i-step 16 keeps 4 row-gathers in flight per quarter.
__global__ __launch_bounds__(256) void gat_node_k(
    const __half* __restrict__ fsfd, const __half* __restrict__ attn_h,
    const int* __restrict__ rowptr, const ushort* __restrict__ nbr,
    float* __restrict__ out)
{
    const int node = blockIdx.x * 4 + (threadIdx.x >> 6);
    const int lane = threadIdx.x & 63;
    const int ql = lane & 15;
    const int q  = lane >> 4;

    const uint4 ufd = *(const uint4*)&fsfd[(size_t)node * 256 + 128 + 8 * ql];
    const __half2 fd0 = u2h(ufd.x), fd1 = u2h(ufd.y), fd2 = u2h(ufd.z), fd3 = u2h(ufd.w);
    const uint4 uav = *(const uint4*)&attn_h[8 * ql];
    const __half2 av0 = u2h(uav.x), av1 = u2h(uav.y), av2 = u2h(uav.z), av3 = u2h(uav.w);
    const __half2 k02 = __float2half2_rn(NEG);

    const int beg = rowptr[node];
    const int end = rowptr[node + 1];

    float den = 0.f;
    __half2 acc0 = u2h(0), acc1 = u2h(0), acc2 = u2h(0), acc3 = u2h(0);

    for (int i = beg; i < end; i += 16) {
        #pragma unroll
        for (int j = 0; j < 4; ++j) {
            const int idx = i + 4 * j + q;
            const bool valid = idx < end;
            const int s = nbr[valid ? idx : end - 1];
            const uint4 u = *(const uint4*)&fsfd[(size_t)s * 256 + 8 * ql];
            const __half2 f0 = u2h(u.x), f1 = u2h(u.y), f2 = u2h(u.z), f3 = u2h(u.w);
            __half2 v0 = __hadd2(f0, fd0), v1 = __hadd2(f1, fd1);
            __half2 v2 = __hadd2(f2, fd2), v3 = __hadd2(f3, fd3);
            v0 = hmax2(v0, __hmul2(v0, k02));
            v1 = hmax2(v1, __hmul2(v1, k02));
            v2 = hmax2(v2, __hmul2(v2, k02));
            v3 = hmax2(v3, __hmul2(v3, k02));
            __half2 sch = __hmul2(v0, av0);
            sch = __hfma2(v1, av1, sch);
            sch = __hfma2(v2, av2, sch);
            sch = __hfma2(v3, av3, sch);
            float sc = __low2float(sch) + __high2float(sch);
            sc = dpp_add<DPP_QUAD_XOR1>(sc);
            sc = dpp_add<DPP_QUAD_XOR2>(sc);
            float ex = __expf(sc);
            ex = valid ? ex : 0.f;
            den += ex;
            const __half2 exh = __float2half2_rn(ex);
            acc0 = __hfma2(exh, f0, acc0);
            acc1 = __hfma2(exh, f1, acc1);
            acc2 = __hfma2(exh, f2, acc2);
            acc3 = __hfma2(exh, f3, acc3);
        }
    }

    den += __shfl_xor(den, 16, 64);
    den += __shfl_xor(den, 32, 64);
    uint ua0 = h2u(acc0), ua1 = h2u(acc1), ua2 = h2u(acc2), ua3 = h2u(acc3);
    ua0 = h2u(__hadd2(u2h(ua0), u2h((uint)__shfl_xor((int)ua0, 16, 64))));
    ua1 = h2u(__hadd2(u2h(ua1), u2h((uint)__shfl_xor((int)ua1, 16, 64))));
    ua2 = h2u(__hadd2(u2h(ua2), u2h((uint)__shfl_xor((int)ua2, 16, 64))));
    ua3 = h2u(__hadd2(u2h(ua3), u2h((uint)__shfl_xor((int)ua3, 16, 64))));
    ua0 = h2u(__hadd2(u2h(ua0), u2h((uint)__shfl_xor((int)ua0, 32, 64))));
    ua1 = h2u(__hadd2(u2h(ua1), u2h((uint)__shfl_xor((int)ua1, 32, 64))));
    ua2 = h2u(__hadd2(u2h(ua2), u2h((uint)__shfl_xor((int)ua2, 32, 64))));
    ua3 = h2u(__hadd2(u2h(ua3), u2h((uint)__shfl_xor((int)ua3, 32, 64))));

    if (q == 0) {
        const float inv = (den > 0.f) ? 1.f / den : 0.f;
        float4 o0, o1;
        o0.x = fmaxf(__low2float(u2h(ua0))  * inv, 0.f);
        o0.y = fmaxf(__high2float(u2h(ua0)) * inv, 0.f);
        o0.z = fmaxf(__low2float(u2h(ua1))  * inv, 0.f);
        o0.w = fmaxf(__high2float(u2h(ua1)) * inv, 0.f);
        o1.x = fmaxf(__low2float(u2h(ua2))  * inv, 0.f);
        o1.y = fmaxf(__high2float(u2h(ua2)) * inv, 0.f);
        o1.z = fmaxf(__low2float(u2h(ua3))  * inv, 0.f);
        o1.w = fmaxf(__high2float(u2h(ua3)) * inv, 0.f);
        *(float4*)&out[(size_t)node * FOUT + 8 * ql] = o0;
        *(float4*)&out[(size_t)node * FOUT + 8 * ql + 4] = o1;
    }
}

extern "C" void kernel_launch(void* const* d_in, const int* in_sizes, int n_in,
                              void* d_out, int out_size, void* d_ws, size_t ws_size,
                              hipStream_t stream)
{
    const float* x    = (const float*)d_in[0];
    const int*   src  = (const int*)d_in[1];
    const int*   dst  = (const int*)d_in[2];
    const float* Wsrc = (const float*)d_in[3];
    const float* bsrc = (const float*)d_in[4];
    const float* Wdst = (const float*)d_in[5];
    const float* bdst = (const float*)d_in[6];
    const float* attn = (const float*)d_in[7];
    float* out = (float*)d_out;

    ushort* Wt      = (ushort*)d_ws;                      // 256*128 bf16
    __half* fsfd    = (__half*)(Wt + 256 * FIN);          // NN*256 f16
    int* chunk_hist = (int*)(fsfd + (size_t)NN * 256);    // NCHUNK*NBKT
    int* bkbase     = chunk_hist + NCHUNK * NBKT;         // NBKT+1
    int* rowptr     = bkbase + NBKT + 1;                  // NN+1
    uint* ebuf      = (uint*)(rowptr + NN + 1);           // NE packed (d<<16)|s
    ushort* nbr     = (ushort*)(ebuf + NE);               // NE u16
    __half* attn_h  = (__half*)(nbr + NE);                // 128 f16

    hist_wt_k<<<NCHUNK + NB_W, 256, 0, stream>>>(dst, chunk_hist, Wsrc, Wdst, Wt, attn, attn_h);
    gemm_scatter_k<<<GB_GRID, 256, 0, stream>>>(x, Wt, bsrc, bdst, fsfd,
                                                dst, src, chunk_hist, bkbase, ebuf);
    binB_k<<<NBKT, 256, 0, stream>>>(ebuf, bkbase, rowptr, nbr);
    gat_node_k<<<(NN + 3) / 4, 256, 0, stream>>>(fsfd, attn_h, rowptr, nbr, out);
}